// Round 3
// baseline (366.292 us; speedup 1.0000x reference)
//
#include <hip/hip_runtime.h>

// Trilinear interpolation, grid (128,128,128,8) f32, 2M random points.
// Round 3: counting-sort a 4B permutation (not 16B records), sub-counter
// atomics to cut contention, XCD-chunked swizzle in the interp kernel.

#define GS   128                    // grid spatial size
#define NBX  32                     // buckets per axis = GS/4
#define NBUCKET (NBX * NBX * NBX)   // 32768
#define NSUB 4                      // sub-counters per bucket
#define NCNT (NBUCKET * NSUB)       // 131072
#define SCAN_THREADS 1024
#define PER_THREAD (NCNT / SCAN_THREADS)  // 128

__device__ __forceinline__ void point_cell(
    float cx, float cy, float cz,
    float b0x, float b0y, float b0z,
    float sx, float sy, float sz,
    int& x0, int& y0, int& z0,
    float& wx, float& wy, float& wz)
{
    float nx = fminf(fmaxf((cx - b0x) / sx, 0.0f), 1.0f);
    float ny = fminf(fmaxf((cy - b0y) / sy, 0.0f), 1.0f);
    float nz = fminf(fmaxf((cz - b0z) / sz, 0.0f), 1.0f);
    float px = nx * (float)(GS - 1);
    float py = ny * (float)(GS - 1);
    float pz = nz * (float)(GS - 1);
    x0 = (int)px; y0 = (int)py; z0 = (int)pz;  // px>=0 -> trunc==floor
    wx = fminf(fmaxf(px - (float)x0, 0.0f), 1.0f);
    wy = fminf(fmaxf(py - (float)y0, 0.0f), 1.0f);
    wz = fminf(fmaxf(pz - (float)z0, 0.0f), 1.0f);
}

__device__ __forceinline__ int counter_of(int x0, int y0, int z0, int i) {
    int b = ((x0 >> 2) * NBX + (y0 >> 2)) * NBX + (z0 >> 2);
    return b * NSUB + (i & (NSUB - 1));
}

// ---------------- K1: histogram (fire-and-forget atomics) ----------------
__global__ __launch_bounds__(256) void k_hist(
    const float* __restrict__ coords,
    const float* __restrict__ bbox_min,
    const float* __restrict__ bbox_max,
    unsigned* __restrict__ hist, int n)
{
    int i = blockIdx.x * blockDim.x + threadIdx.x;
    if (i >= n) return;
    const float eps = 1e-6f;
    float b0x = bbox_min[0], b0y = bbox_min[1], b0z = bbox_min[2];
    float sx = fmaxf(bbox_max[0] - b0x, eps);
    float sy = fmaxf(bbox_max[1] - b0y, eps);
    float sz = fmaxf(bbox_max[2] - b0z, eps);
    int x0, y0, z0; float wx, wy, wz;
    point_cell(coords[3*i], coords[3*i+1], coords[3*i+2],
               b0x, b0y, b0z, sx, sy, sz, x0, y0, z0, wx, wy, wz);
    atomicAdd(&hist[counter_of(x0, y0, z0, i)], 1u);
}

// ------- K2: exclusive scan over 131072 counters (1 block, re-read) -------
__global__ __launch_bounds__(SCAN_THREADS) void k_scan(
    const unsigned* __restrict__ hist,
    unsigned* __restrict__ offs)
{
    __shared__ unsigned s[SCAN_THREADS];
    int t = threadIdx.x;
    unsigned sum = 0;
    for (int j = 0; j < PER_THREAD; ++j) sum += hist[t * PER_THREAD + j];
    s[t] = sum;
    __syncthreads();
    for (int d = 1; d < SCAN_THREADS; d <<= 1) {
        unsigned v = (t >= d) ? s[t - d] : 0u;
        __syncthreads();
        s[t] += v;
        __syncthreads();
    }
    unsigned excl = (t == 0) ? 0u : s[t - 1];
    for (int j = 0; j < PER_THREAD; ++j) {
        unsigned h = hist[t * PER_THREAD + j];
        offs[t * PER_THREAD + j] = excl;
        excl += h;
    }
}

// ---------------- K3: scatter 4B perm entries ----------------
__global__ __launch_bounds__(256) void k_scatter(
    const float* __restrict__ coords,
    const float* __restrict__ bbox_min,
    const float* __restrict__ bbox_max,
    unsigned* __restrict__ offs,
    unsigned* __restrict__ perm, int n)
{
    int i = blockIdx.x * blockDim.x + threadIdx.x;
    if (i >= n) return;
    const float eps = 1e-6f;
    float b0x = bbox_min[0], b0y = bbox_min[1], b0z = bbox_min[2];
    float sx = fmaxf(bbox_max[0] - b0x, eps);
    float sy = fmaxf(bbox_max[1] - b0y, eps);
    float sz = fmaxf(bbox_max[2] - b0z, eps);
    int x0, y0, z0; float wx, wy, wz;
    point_cell(coords[3*i], coords[3*i+1], coords[3*i+2],
               b0x, b0y, b0z, sx, sy, sz, x0, y0, z0, wx, wy, wz);
    unsigned pos = atomicAdd(&offs[counter_of(x0, y0, z0, i)], 1u);
    perm[pos] = (unsigned)i;
}

// ---------------- K4: interpolate in sorted order ----------------
__global__ __launch_bounds__(256) void k_interp(
    const unsigned* __restrict__ perm,
    const float* __restrict__ coords,
    const float* __restrict__ grid,
    const float* __restrict__ bbox_min,
    const float* __restrict__ bbox_max,
    float* __restrict__ out, int n)
{
    // bijective XCD-chunked swizzle: XCD k gets a contiguous chunk of the
    // sorted point range -> its L2 streams one contiguous x-slab of the grid
    int nwg = gridDim.x;
    int ob  = blockIdx.x;
    int q = nwg >> 3, r = nwg & 7;
    int xcd = ob & 7, sub = ob >> 3;
    int bid = (xcd < r ? xcd * (q + 1) : r * (q + 1) + (xcd - r) * q) + sub;
    int i = bid * 256 + (int)threadIdx.x;
    if (i >= n) return;

    const float eps = 1e-6f;
    float b0x = bbox_min[0], b0y = bbox_min[1], b0z = bbox_min[2];
    float sx = fmaxf(bbox_max[0] - b0x, eps);
    float sy = fmaxf(bbox_max[1] - b0y, eps);
    float sz = fmaxf(bbox_max[2] - b0z, eps);

    unsigned o = perm[i];
    float cx = coords[3*o], cy = coords[3*o+1], cz = coords[3*o+2];
    int x0, y0, z0; float wx, wy, wz;
    point_cell(cx, cy, cz, b0x, b0y, b0z, sx, sy, sz, x0, y0, z0, wx, wy, wz);
    int x1 = min(x0 + 1, GS - 1);
    int y1 = min(y0 + 1, GS - 1);
    int z1 = min(z0 + 1, GS - 1);

    float ux = 1.0f - wx, uy = 1.0f - wy, uz = 1.0f - wz;
    float w000 = ux*uy*uz, w100 = wx*uy*uz, w010 = ux*wy*uz, w110 = wx*wy*uz;
    float w001 = ux*uy*wz, w101 = wx*uy*wz, w011 = ux*wy*wz, w111 = wx*wy*wz;

    const float4* g4 = (const float4*)grid;
    long long bx0 = (long long)x0 * GS;
    long long bx1 = (long long)x1 * GS;
    long long p000 = ((bx0 + y0) * GS + z0) * 2;
    long long p100 = ((bx1 + y0) * GS + z0) * 2;
    long long p010 = ((bx0 + y1) * GS + z0) * 2;
    long long p110 = ((bx1 + y1) * GS + z0) * 2;
    long long p001 = ((bx0 + y0) * GS + z1) * 2;
    long long p101 = ((bx1 + y0) * GS + z1) * 2;
    long long p011 = ((bx0 + y1) * GS + z1) * 2;
    long long p111 = ((bx1 + y1) * GS + z1) * 2;

    float4 a0 = g4[p000], a1 = g4[p000 + 1];
    float4 b0 = g4[p100], b1 = g4[p100 + 1];
    float4 c0 = g4[p010], c1 = g4[p010 + 1];
    float4 d0 = g4[p110], d1 = g4[p110 + 1];
    float4 e0 = g4[p001], e1 = g4[p001 + 1];
    float4 f0 = g4[p101], f1 = g4[p101 + 1];
    float4 h0 = g4[p011], h1 = g4[p011 + 1];
    float4 k0 = g4[p111], k1 = g4[p111 + 1];

    float4 o0, o1;
    o0.x = a0.x*w000 + b0.x*w100 + c0.x*w010 + d0.x*w110 + e0.x*w001 + f0.x*w101 + h0.x*w011 + k0.x*w111;
    o0.y = a0.y*w000 + b0.y*w100 + c0.y*w010 + d0.y*w110 + e0.y*w001 + f0.y*w101 + h0.y*w011 + k0.y*w111;
    o0.z = a0.z*w000 + b0.z*w100 + c0.z*w010 + d0.z*w110 + e0.z*w001 + f0.z*w101 + h0.z*w011 + k0.z*w111;
    o0.w = a0.w*w000 + b0.w*w100 + c0.w*w010 + d0.w*w110 + e0.w*w001 + f0.w*w101 + h0.w*w011 + k0.w*w111;
    o1.x = a1.x*w000 + b1.x*w100 + c1.x*w010 + d1.x*w110 + e1.x*w001 + f1.x*w101 + h1.x*w011 + k1.x*w111;
    o1.y = a1.y*w000 + b1.y*w100 + c1.y*w010 + d1.y*w110 + e1.y*w001 + f1.y*w101 + h1.y*w011 + k1.y*w111;
    o1.z = a1.z*w000 + b1.z*w100 + c1.z*w010 + d1.z*w110 + e1.z*w001 + f1.z*w101 + h1.z*w011 + k1.z*w111;
    o1.w = a1.w*w000 + b1.w*w100 + c1.w*w010 + d1.w*w110 + e1.w*w001 + f1.w*w101 + h1.w*w011 + k1.w*w111;

    float4* out4 = (float4*)out;
    out4[(long long)o * 2 + 0] = o0;
    out4[(long long)o * 2 + 1] = o1;
}

// ---------------- fallback: direct (round-1) kernel ----------------
__global__ __launch_bounds__(256) void trilerp_direct(
    const float* __restrict__ coords,
    const float* __restrict__ grid,
    const float* __restrict__ bbox_min,
    const float* __restrict__ bbox_max,
    float* __restrict__ out, int n)
{
    int i = blockIdx.x * blockDim.x + threadIdx.x;
    if (i >= n) return;
    const float eps = 1e-6f;
    float b0x = bbox_min[0], b0y = bbox_min[1], b0z = bbox_min[2];
    float sx = fmaxf(bbox_max[0] - b0x, eps);
    float sy = fmaxf(bbox_max[1] - b0y, eps);
    float sz = fmaxf(bbox_max[2] - b0z, eps);
    int x0, y0, z0; float wx, wy, wz;
    point_cell(coords[3*i], coords[3*i+1], coords[3*i+2],
               b0x, b0y, b0z, sx, sy, sz, x0, y0, z0, wx, wy, wz);
    int x1 = min(x0 + 1, GS - 1);
    int y1 = min(y0 + 1, GS - 1);
    int z1 = min(z0 + 1, GS - 1);
    float ux = 1.0f - wx, uy = 1.0f - wy, uz = 1.0f - wz;
    float w000 = ux*uy*uz, w100 = wx*uy*uz, w010 = ux*wy*uz, w110 = wx*wy*uz;
    float w001 = ux*uy*wz, w101 = wx*uy*wz, w011 = ux*wy*wz, w111 = wx*wy*wz;
    const float4* g4 = (const float4*)grid;
    long long bx0 = (long long)x0 * GS, bx1 = (long long)x1 * GS;
    long long p000 = ((bx0 + y0) * GS + z0) * 2, p100 = ((bx1 + y0) * GS + z0) * 2;
    long long p010 = ((bx0 + y1) * GS + z0) * 2, p110 = ((bx1 + y1) * GS + z0) * 2;
    long long p001 = ((bx0 + y0) * GS + z1) * 2, p101 = ((bx1 + y0) * GS + z1) * 2;
    long long p011 = ((bx0 + y1) * GS + z1) * 2, p111 = ((bx1 + y1) * GS + z1) * 2;
    float4 a0 = g4[p000], a1 = g4[p000+1], b0 = g4[p100], b1 = g4[p100+1];
    float4 c0 = g4[p010], c1 = g4[p010+1], d0 = g4[p110], d1 = g4[p110+1];
    float4 e0 = g4[p001], e1 = g4[p001+1], f0 = g4[p101], f1 = g4[p101+1];
    float4 h0 = g4[p011], h1 = g4[p011+1], k0 = g4[p111], k1 = g4[p111+1];
    float4 o0, o1;
    o0.x = a0.x*w000 + b0.x*w100 + c0.x*w010 + d0.x*w110 + e0.x*w001 + f0.x*w101 + h0.x*w011 + k0.x*w111;
    o0.y = a0.y*w000 + b0.y*w100 + c0.y*w010 + d0.y*w110 + e0.y*w001 + f0.y*w101 + h0.y*w011 + k0.y*w111;
    o0.z = a0.z*w000 + b0.z*w100 + c0.z*w010 + d0.z*w110 + e0.z*w001 + f0.z*w101 + h0.z*w011 + k0.z*w111;
    o0.w = a0.w*w000 + b0.w*w100 + c0.w*w010 + d0.w*w110 + e0.w*w001 + f0.w*w101 + h0.w*w011 + k0.w*w111;
    o1.x = a1.x*w000 + b1.x*w100 + c1.x*w010 + d1.x*w110 + e1.x*w001 + f1.x*w101 + h1.x*w011 + k1.x*w111;
    o1.y = a1.y*w000 + b1.y*w100 + c1.y*w010 + d1.y*w110 + e1.y*w001 + f1.y*w101 + h1.y*w011 + k1.y*w111;
    o1.z = a1.z*w000 + b1.z*w100 + c1.z*w010 + d1.z*w110 + e1.z*w001 + f1.z*w101 + h1.z*w011 + k1.z*w111;
    o1.w = a1.w*w000 + b1.w*w100 + c1.w*w010 + d1.w*w110 + e1.w*w001 + f1.w*w101 + h1.w*w011 + k1.w*w111;
    float4* out4 = (float4*)out;
    out4[(long long)i * 2 + 0] = o0;
    out4[(long long)i * 2 + 1] = o1;
}

extern "C" void kernel_launch(void* const* d_in, const int* in_sizes, int n_in,
                              void* d_out, int out_size, void* d_ws, size_t ws_size,
                              hipStream_t stream) {
    const float* coords   = (const float*)d_in[0];
    const float* grid     = (const float*)d_in[1];
    const float* bbox_min = (const float*)d_in[2];
    const float* bbox_max = (const float*)d_in[3];
    float* out = (float*)d_out;

    int n = in_sizes[0] / 3;
    int block = 256;
    int nblocks = (n + block - 1) / block;

    size_t cnt_bytes = (size_t)NCNT * 4;             // 512 KB
    size_t offs_off  = cnt_bytes;
    size_t perm_off  = cnt_bytes * 2;                // 1 MB
    size_t needed    = perm_off + (size_t)n * 4;     // + 8 MB

    if (ws_size < needed) {
        trilerp_direct<<<nblocks, block, 0, stream>>>(coords, grid, bbox_min, bbox_max, out, n);
        return;
    }

    unsigned* hist = (unsigned*)d_ws;
    unsigned* offs = (unsigned*)((char*)d_ws + offs_off);
    unsigned* perm = (unsigned*)((char*)d_ws + perm_off);

    hipMemsetAsync(hist, 0, cnt_bytes, stream);
    k_hist<<<nblocks, block, 0, stream>>>(coords, bbox_min, bbox_max, hist, n);
    k_scan<<<1, SCAN_THREADS, 0, stream>>>(hist, offs);
    k_scatter<<<nblocks, block, 0, stream>>>(coords, bbox_min, bbox_max, offs, perm, n);
    k_interp<<<nblocks, block, 0, stream>>>(perm, coords, grid, bbox_min, bbox_max, out, n);
}

// Round 4
// 167.528 us; speedup vs baseline: 2.1865x; 2.1865x over previous
//
#include <hip/hip_runtime.h>

// Trilinear interpolation, grid (128,128,128,8) f32, 2M random points.
// Round 4: sort into 32 coarse x-slab buckets (slab fits per-XCD L2) with
// BLOCK-AGGREGATED scatter: LDS histogram + 32 range-reserve atomics/block +
// LDS-staged grouped burst writes. Full 16B records so interp reads linearly.

#define GS   128
#define NB   32          // x-slab buckets (4 cells thick): slab+boundary ~2.5MB < 4MB L2
#define K3_PTS 1024      // points per scatter/hist block (256 threads x 4)

__device__ __forceinline__ int slab_of(float cx, float b0x, float sx) {
    float nx = fminf(fmaxf((cx - b0x) / sx, 0.0f), 1.0f);
    int x0 = (int)(nx * (float)(GS - 1));
    return x0 >> 2;
}

// ---------------- K1: bucket histogram (LDS-aggregated) ----------------
__global__ __launch_bounds__(256) void k_hist(
    const float* __restrict__ coords,
    const float* __restrict__ bbox_min,
    const float* __restrict__ bbox_max,
    unsigned* __restrict__ hist, int n)
{
    __shared__ unsigned h[NB];
    int t = threadIdx.x;
    if (t < NB) h[t] = 0;
    __syncthreads();
    float b0x = bbox_min[0];
    float sx  = fmaxf(bbox_max[0] - b0x, 1e-6f);
    long long base = (long long)blockIdx.x * K3_PTS;
#pragma unroll
    for (int k = 0; k < 4; ++k) {
        long long i = base + k * 256 + t;
        if (i < n) atomicAdd(&h[slab_of(coords[3 * i], b0x, sx)], 1u);
    }
    __syncthreads();
    if (t < NB && h[t]) atomicAdd(&hist[t], h[t]);
}

// ---------------- K2: exclusive scan over 32 totals ----------------
__global__ void k_scan32(const unsigned* __restrict__ hist,
                         unsigned* __restrict__ cursor)
{
    if (threadIdx.x == 0) {
        unsigned acc = 0;
        for (int j = 0; j < NB; ++j) { unsigned v = hist[j]; cursor[j] = acc; acc += v; }
    }
}

// ---------------- K3: block-aggregated scatter of 16B records ----------------
__global__ __launch_bounds__(256) void k_scatter(
    const float* __restrict__ coords,
    const float* __restrict__ bbox_min,
    const float* __restrict__ bbox_max,
    unsigned* __restrict__ cursor,
    float4* __restrict__ recs, int n)
{
    __shared__ float4 srec[K3_PTS];          // 16 KB staged records
    __shared__ unsigned char sbkt[K3_PTS];   // bucket of each staged slot
    __shared__ unsigned cnt[NB], lbase[NB], gbase[NB];

    int t = threadIdx.x;
    if (t < NB) cnt[t] = 0;
    __syncthreads();

    float b0x = bbox_min[0];
    float sx  = fmaxf(bbox_max[0] - b0x, 1e-6f);
    long long base = (long long)blockIdx.x * K3_PTS;
    int m = (int)min((long long)K3_PTS, (long long)n - base);

    float cx[4], cy[4], cz[4];
    int bb[4]; unsigned rr[4];
#pragma unroll
    for (int k = 0; k < 4; ++k) {
        int j = k * 256 + t;
        if (j < m) {
            long long i = base + j;
            cx[k] = coords[3 * i];
            cy[k] = coords[3 * i + 1];
            cz[k] = coords[3 * i + 2];
            bb[k] = slab_of(cx[k], b0x, sx);
            rr[k] = atomicAdd(&cnt[bb[k]], 1u);
        }
    }
    __syncthreads();   // cnt final

    if (t == 0) {
        unsigned acc = 0;
        for (int j = 0; j < NB; ++j) { lbase[j] = acc; acc += cnt[j]; }
    }
    if (t < NB && cnt[t]) gbase[t] = atomicAdd(&cursor[t], cnt[t]);
    __syncthreads();   // lbase, gbase visible

#pragma unroll
    for (int k = 0; k < 4; ++k) {
        int j = k * 256 + t;
        if (j < m) {
            unsigned slot = lbase[bb[k]] + rr[k];
            float4 r; r.x = cx[k]; r.y = cy[k]; r.z = cz[k];
            r.w = __uint_as_float((unsigned)(base + j));
            srec[slot] = r;
            sbkt[slot] = (unsigned char)bb[k];
        }
    }
    __syncthreads();   // staged

    // grouped burst write: consecutive slots of one bucket -> consecutive global
#pragma unroll
    for (int k = 0; k < 4; ++k) {
        int j = k * 256 + t;
        if (j < m) {
            int b = sbkt[j];
            recs[gbase[b] + (unsigned)j - lbase[b]] = srec[j];
        }
    }
}

// ---------------- K4: interpolate in sorted (slab) order ----------------
__global__ __launch_bounds__(256) void k_interp(
    const float4* __restrict__ recs,
    const float* __restrict__ grid,
    const float* __restrict__ bbox_min,
    const float* __restrict__ bbox_max,
    float* __restrict__ out, int n)
{
    // bijective XCD-chunked swizzle: each XCD walks a contiguous chunk of the
    // sorted order -> its private L2 streams one grid slab at a time
    int nwg = gridDim.x;
    int ob  = blockIdx.x;
    int q = nwg >> 3, r = nwg & 7;
    int xcd = ob & 7, sub = ob >> 3;
    int bid = (xcd < r ? xcd * (q + 1) : r * (q + 1) + (xcd - r) * q) + sub;
    long long i = (long long)bid * 256 + threadIdx.x;
    if (i >= n) return;

    const float eps = 1e-6f;
    float b0x = bbox_min[0], b0y = bbox_min[1], b0z = bbox_min[2];
    float sx = fmaxf(bbox_max[0] - b0x, eps);
    float sy = fmaxf(bbox_max[1] - b0y, eps);
    float sz = fmaxf(bbox_max[2] - b0z, eps);

    float4 rec = recs[i];
    unsigned orig = __float_as_uint(rec.w);

    float nx = fminf(fmaxf((rec.x - b0x) / sx, 0.0f), 1.0f);
    float ny = fminf(fmaxf((rec.y - b0y) / sy, 0.0f), 1.0f);
    float nz = fminf(fmaxf((rec.z - b0z) / sz, 0.0f), 1.0f);
    float px = nx * (float)(GS - 1);
    float py = ny * (float)(GS - 1);
    float pz = nz * (float)(GS - 1);
    int x0 = (int)px, y0 = (int)py, z0 = (int)pz;
    int x1 = min(x0 + 1, GS - 1);
    int y1 = min(y0 + 1, GS - 1);
    int z1 = min(z0 + 1, GS - 1);
    float wx = fminf(fmaxf(px - (float)x0, 0.0f), 1.0f);
    float wy = fminf(fmaxf(py - (float)y0, 0.0f), 1.0f);
    float wz = fminf(fmaxf(pz - (float)z0, 0.0f), 1.0f);

    float ux = 1.0f - wx, uy = 1.0f - wy, uz = 1.0f - wz;
    float w000 = ux*uy*uz, w100 = wx*uy*uz, w010 = ux*wy*uz, w110 = wx*wy*uz;
    float w001 = ux*uy*wz, w101 = wx*uy*wz, w011 = ux*wy*wz, w111 = wx*wy*wz;

    const float4* g4 = (const float4*)grid;
    int bx0 = x0 * GS, bx1 = x1 * GS;
    int p000 = ((bx0 + y0) * GS + z0) * 2;
    int p100 = ((bx1 + y0) * GS + z0) * 2;
    int p010 = ((bx0 + y1) * GS + z0) * 2;
    int p110 = ((bx1 + y1) * GS + z0) * 2;
    int p001 = ((bx0 + y0) * GS + z1) * 2;
    int p101 = ((bx1 + y0) * GS + z1) * 2;
    int p011 = ((bx0 + y1) * GS + z1) * 2;
    int p111 = ((bx1 + y1) * GS + z1) * 2;

    float4 a0 = g4[p000], a1 = g4[p000 + 1];
    float4 b0 = g4[p100], b1 = g4[p100 + 1];
    float4 c0 = g4[p010], c1 = g4[p010 + 1];
    float4 d0 = g4[p110], d1 = g4[p110 + 1];
    float4 e0 = g4[p001], e1 = g4[p001 + 1];
    float4 f0 = g4[p101], f1 = g4[p101 + 1];
    float4 h0 = g4[p011], h1 = g4[p011 + 1];
    float4 k0 = g4[p111], k1 = g4[p111 + 1];

    float4 o0, o1;
    o0.x = a0.x*w000 + b0.x*w100 + c0.x*w010 + d0.x*w110 + e0.x*w001 + f0.x*w101 + h0.x*w011 + k0.x*w111;
    o0.y = a0.y*w000 + b0.y*w100 + c0.y*w010 + d0.y*w110 + e0.y*w001 + f0.y*w101 + h0.y*w011 + k0.y*w111;
    o0.z = a0.z*w000 + b0.z*w100 + c0.z*w010 + d0.z*w110 + e0.z*w001 + f0.z*w101 + h0.z*w011 + k0.z*w111;
    o0.w = a0.w*w000 + b0.w*w100 + c0.w*w010 + d0.w*w110 + e0.w*w001 + f0.w*w101 + h0.w*w011 + k0.w*w111;
    o1.x = a1.x*w000 + b1.x*w100 + c1.x*w010 + d1.x*w110 + e1.x*w001 + f1.x*w101 + h1.x*w011 + k1.x*w111;
    o1.y = a1.y*w000 + b1.y*w100 + c1.y*w010 + d1.y*w110 + e1.y*w001 + f1.y*w101 + h1.y*w011 + k1.y*w111;
    o1.z = a1.z*w000 + b1.z*w100 + c1.z*w010 + d1.z*w110 + e1.z*w001 + f1.z*w101 + h1.z*w011 + k1.z*w111;
    o1.w = a1.w*w000 + b1.w*w100 + c1.w*w010 + d1.w*w110 + e1.w*w001 + f1.w*w101 + h1.w*w011 + k1.w*w111;

    float4* out4 = (float4*)out;
    out4[(long long)orig * 2 + 0] = o0;
    out4[(long long)orig * 2 + 1] = o1;
}

// ---------------- fallback: direct (round-1) kernel ----------------
__global__ __launch_bounds__(256) void trilerp_direct(
    const float* __restrict__ coords,
    const float* __restrict__ grid,
    const float* __restrict__ bbox_min,
    const float* __restrict__ bbox_max,
    float* __restrict__ out, int n)
{
    int i = blockIdx.x * blockDim.x + threadIdx.x;
    if (i >= n) return;
    const float eps = 1e-6f;
    float b0x = bbox_min[0], b0y = bbox_min[1], b0z = bbox_min[2];
    float sx = fmaxf(bbox_max[0] - b0x, eps);
    float sy = fmaxf(bbox_max[1] - b0y, eps);
    float sz = fmaxf(bbox_max[2] - b0z, eps);
    float nx = fminf(fmaxf((coords[3*i] - b0x) / sx, 0.0f), 1.0f);
    float ny = fminf(fmaxf((coords[3*i+1] - b0y) / sy, 0.0f), 1.0f);
    float nz = fminf(fmaxf((coords[3*i+2] - b0z) / sz, 0.0f), 1.0f);
    float px = nx * (float)(GS - 1), py = ny * (float)(GS - 1), pz = nz * (float)(GS - 1);
    int x0 = (int)px, y0 = (int)py, z0 = (int)pz;
    int x1 = min(x0 + 1, GS - 1), y1 = min(y0 + 1, GS - 1), z1 = min(z0 + 1, GS - 1);
    float wx = fminf(fmaxf(px - (float)x0, 0.0f), 1.0f);
    float wy = fminf(fmaxf(py - (float)y0, 0.0f), 1.0f);
    float wz = fminf(fmaxf(pz - (float)z0, 0.0f), 1.0f);
    float ux = 1.0f - wx, uy = 1.0f - wy, uz = 1.0f - wz;
    float w000 = ux*uy*uz, w100 = wx*uy*uz, w010 = ux*wy*uz, w110 = wx*wy*uz;
    float w001 = ux*uy*wz, w101 = wx*uy*wz, w011 = ux*wy*wz, w111 = wx*wy*wz;
    const float4* g4 = (const float4*)grid;
    int bx0 = x0 * GS, bx1 = x1 * GS;
    int p000 = ((bx0 + y0) * GS + z0) * 2, p100 = ((bx1 + y0) * GS + z0) * 2;
    int p010 = ((bx0 + y1) * GS + z0) * 2, p110 = ((bx1 + y1) * GS + z0) * 2;
    int p001 = ((bx0 + y0) * GS + z1) * 2, p101 = ((bx1 + y0) * GS + z1) * 2;
    int p011 = ((bx0 + y1) * GS + z1) * 2, p111 = ((bx1 + y1) * GS + z1) * 2;
    float4 a0 = g4[p000], a1 = g4[p000+1], b0 = g4[p100], b1 = g4[p100+1];
    float4 c0 = g4[p010], c1 = g4[p010+1], d0 = g4[p110], d1 = g4[p110+1];
    float4 e0 = g4[p001], e1 = g4[p001+1], f0 = g4[p101], f1 = g4[p101+1];
    float4 h0 = g4[p011], h1 = g4[p011+1], k0 = g4[p111], k1 = g4[p111+1];
    float4 o0, o1;
    o0.x = a0.x*w000 + b0.x*w100 + c0.x*w010 + d0.x*w110 + e0.x*w001 + f0.x*w101 + h0.x*w011 + k0.x*w111;
    o0.y = a0.y*w000 + b0.y*w100 + c0.y*w010 + d0.y*w110 + e0.y*w001 + f0.y*w101 + h0.y*w011 + k0.y*w111;
    o0.z = a0.z*w000 + b0.z*w100 + c0.z*w010 + d0.z*w110 + e0.z*w001 + f0.z*w101 + h0.z*w011 + k0.z*w111;
    o0.w = a0.w*w000 + b0.w*w100 + c0.w*w010 + d0.w*w110 + e0.w*w001 + f0.w*w101 + h0.w*w011 + k0.w*w111;
    o1.x = a1.x*w000 + b1.x*w100 + c1.x*w010 + d1.x*w110 + e1.x*w001 + f1.x*w101 + h1.x*w011 + k1.x*w111;
    o1.y = a1.y*w000 + b1.y*w100 + c1.y*w010 + d1.y*w110 + e1.y*w001 + f1.y*w101 + h1.y*w011 + k1.y*w111;
    o1.z = a1.z*w000 + b1.z*w100 + c1.z*w010 + d1.z*w110 + e1.z*w001 + f1.z*w101 + h1.z*w011 + k1.z*w111;
    o1.w = a1.w*w000 + b1.w*w100 + c1.w*w010 + d1.w*w110 + e1.w*w001 + f1.w*w101 + h1.w*w011 + k1.w*w111;
    float4* out4 = (float4*)out;
    out4[(long long)i * 2 + 0] = o0;
    out4[(long long)i * 2 + 1] = o1;
}

extern "C" void kernel_launch(void* const* d_in, const int* in_sizes, int n_in,
                              void* d_out, int out_size, void* d_ws, size_t ws_size,
                              hipStream_t stream) {
    const float* coords   = (const float*)d_in[0];
    const float* grid     = (const float*)d_in[1];
    const float* bbox_min = (const float*)d_in[2];
    const float* bbox_max = (const float*)d_in[3];
    float* out = (float*)d_out;

    int n = in_sizes[0] / 3;

    size_t hist_off   = 0;                  // 32 u32 (pad to 256B)
    size_t cursor_off = 256;
    size_t recs_off   = 512;
    size_t needed     = recs_off + (size_t)n * 16;

    if (ws_size < needed) {
        int nblocks = (n + 255) / 256;
        trilerp_direct<<<nblocks, 256, 0, stream>>>(coords, grid, bbox_min, bbox_max, out, n);
        return;
    }

    unsigned* hist   = (unsigned*)((char*)d_ws + hist_off);
    unsigned* cursor = (unsigned*)((char*)d_ws + cursor_off);
    float4*   recs   = (float4*)((char*)d_ws + recs_off);

    int nb_k13 = (n + K3_PTS - 1) / K3_PTS;   // 1954
    int nb_k4  = (n + 255) / 256;             // 7813

    hipMemsetAsync(hist, 0, NB * sizeof(unsigned), stream);
    k_hist   <<<nb_k13, 256, 0, stream>>>(coords, bbox_min, bbox_max, hist, n);
    k_scan32 <<<1, 64, 0, stream>>>(hist, cursor);
    k_scatter<<<nb_k13, 256, 0, stream>>>(coords, bbox_min, bbox_max, cursor, recs, n);
    k_interp <<<nb_k4, 256, 0, stream>>>(recs, grid, bbox_min, bbox_max, out, n);
}